// Round 1
// baseline (13906.854 us; speedup 1.0000x reference)
//
#include <hip/hip_runtime.h>
#include <hip/hip_bf16.h>
#include <cstdint>

#define N_ROWS   65536
#define EDIM     128
#define CBSZ     256
#define NLEV     4

// ============================================================================
// SGEMM: C[R x M] = act(A[R x K] @ W[K x M] + bias),  fp32, 128x128 tile,
// 256 threads, 8x8 microtile, BK=16.  K%16==0, M%128==0, R%128==0 required.
// ============================================================================
template<int RELU>
__global__ __launch_bounds__(256)
void sgemm128(const float* __restrict__ A, const float* __restrict__ W,
              const float* __restrict__ bias, float* __restrict__ C,
              int K, int M) {
    __shared__ float As[16][132];   // [k][row], pad 4 -> 2-way max on store
    __shared__ float Ws[16][128];   // [k][col]

    const int  t  = threadIdx.x;
    const int  bm = blockIdx.x * 128;            // col offset
    const long bn = (long)blockIdx.y * 128;      // row offset
    const int  tx = t & 15, ty = t >> 4;

    float acc[8][8];
#pragma unroll
    for (int i = 0; i < 8; ++i)
#pragma unroll
        for (int j = 0; j < 8; ++j) acc[i][j] = 0.f;

    for (int k0 = 0; k0 < K; k0 += 16) {
        // A tile: 128 rows x 16 k = 512 float4, 2 per thread
#pragma unroll
        for (int i = 0; i < 2; ++i) {
            int e   = t + i * 256;
            int row = e >> 2;
            int kq  = (e & 3) << 2;
            float4 v = *reinterpret_cast<const float4*>(&A[(bn + row) * K + k0 + kq]);
            As[kq + 0][row] = v.x; As[kq + 1][row] = v.y;
            As[kq + 2][row] = v.z; As[kq + 3][row] = v.w;
        }
        // W tile: 16 k x 128 cols = 512 float4, 2 per thread
#pragma unroll
        for (int i = 0; i < 2; ++i) {
            int e  = t + i * 256;
            int kr = e >> 5;
            int mq = (e & 31) << 2;
            *reinterpret_cast<float4*>(&Ws[kr][mq]) =
                *reinterpret_cast<const float4*>(&W[(long)(k0 + kr) * M + bm + mq]);
        }
        __syncthreads();
#pragma unroll
        for (int k = 0; k < 16; ++k) {
            float a[8], b[8];
            *reinterpret_cast<float4*>(&a[0]) = *reinterpret_cast<const float4*>(&As[k][ty * 4]);
            *reinterpret_cast<float4*>(&a[4]) = *reinterpret_cast<const float4*>(&As[k][64 + ty * 4]);
            *reinterpret_cast<float4*>(&b[0]) = *reinterpret_cast<const float4*>(&Ws[k][tx * 4]);
            *reinterpret_cast<float4*>(&b[4]) = *reinterpret_cast<const float4*>(&Ws[k][64 + tx * 4]);
#pragma unroll
            for (int i = 0; i < 8; ++i)
#pragma unroll
                for (int j = 0; j < 8; ++j)
                    acc[i][j] = fmaf(a[i], b[j], acc[i][j]);
        }
        __syncthreads();
    }

#pragma unroll
    for (int i = 0; i < 8; ++i) {
        long row = bn + ((i < 4) ? (ty * 4 + i) : (64 + ty * 4 + (i - 4)));
#pragma unroll
        for (int jh = 0; jh < 2; ++jh) {
            int col = bm + (jh ? (64 + tx * 4) : (tx * 4));
            float4 bb = *reinterpret_cast<const float4*>(&bias[col]);
            float4 v;
            v.x = acc[i][jh * 4 + 0] + bb.x;
            v.y = acc[i][jh * 4 + 1] + bb.y;
            v.z = acc[i][jh * 4 + 2] + bb.z;
            v.w = acc[i][jh * 4 + 3] + bb.w;
            if (RELU) {
                v.x = fmaxf(v.x, 0.f); v.y = fmaxf(v.y, 0.f);
                v.z = fmaxf(v.z, 0.f); v.w = fmaxf(v.w, 0.f);
            }
            *reinterpret_cast<float4*>(&C[row * M + col]) = v;
        }
    }
}

// ============================================================================
// VQ level: for each row r, find argmin_j ||res_r - cb_j||^2 over 256 codes,
// write new residual, index (as float) and per-wave loss partial.
// Codebook staged transposed in LDS: ct[dim][code], stride 260 (pad 4).
// One wave per row, lane owns codes {4*lane .. 4*lane+3}; rows processed in
// pairs so one ct read feeds 2 rows.  Grid: 256 blocks x 512 threads.
// ============================================================================
__global__ __launch_bounds__(512)
void vq_level(const float* __restrict__ resin, float* __restrict__ resout,
              const float* __restrict__ codebooks, int level,
              float* __restrict__ loss_part, float* __restrict__ idxf) {
    __shared__ float ct[EDIM][CBSZ + 4];
    __shared__ float cnorm[CBSZ];
    __shared__ float res_row[8][2][EDIM];

    const float* cb = codebooks + (long)level * CBSZ * EDIM;

    // stage codebook (coalesced global read, transposed LDS write)
    for (int e = threadIdx.x; e < CBSZ * EDIM; e += 512) {
        int j = e >> 7, d = e & 127;
        ct[d][j] = cb[e];
    }
    __syncthreads();
    for (int j = threadIdx.x; j < CBSZ; j += 512) {
        float s = 0.f;
        for (int d = 0; d < EDIM; ++d) s = fmaf(ct[d][j], ct[d][j], s);
        cnorm[j] = s;
    }
    __syncthreads();

    const int w    = threadIdx.x >> 6;
    const int lane = threadIdx.x & 63;
    const int wg   = blockIdx.x * 8 + w;   // 0..2047
    const int jb   = lane * 4;
    float local_loss = 0.f;

    for (int p = 0; p < 16; ++p) {
        const long rA = (long)wg + (long)(2 * p) * 2048;
        const long rB = rA + 2048;

        float2 rvA = *reinterpret_cast<const float2*>(&resin[rA * EDIM + 2 * lane]);
        float2 rvB = *reinterpret_cast<const float2*>(&resin[rB * EDIM + 2 * lane]);
        res_row[w][0][2 * lane] = rvA.x; res_row[w][0][2 * lane + 1] = rvA.y;
        res_row[w][1][2 * lane] = rvB.x; res_row[w][1][2 * lane + 1] = rvB.y;

        float rrA = rvA.x * rvA.x + rvA.y * rvA.y;
        float rrB = rvB.x * rvB.x + rvB.y * rvB.y;
#pragma unroll
        for (int off = 32; off; off >>= 1) {
            rrA += __shfl_xor(rrA, off);
            rrB += __shfl_xor(rrB, off);
        }

        float dA0 = 0, dA1 = 0, dA2 = 0, dA3 = 0;
        float dB0 = 0, dB1 = 0, dB2 = 0, dB3 = 0;
        for (int d = 0; d < EDIM; d += 4) {
            float4 ra = *reinterpret_cast<const float4*>(&res_row[w][0][d]);
            float4 rb = *reinterpret_cast<const float4*>(&res_row[w][1][d]);
            const float* rap = &ra.x;
            const float* rbp = &rb.x;
#pragma unroll
            for (int dd = 0; dd < 4; ++dd) {
                float4 cv = *reinterpret_cast<const float4*>(&ct[d + dd][jb]);
                float rax = rap[dd], rbx = rbp[dd];
                dA0 = fmaf(rax, cv.x, dA0); dA1 = fmaf(rax, cv.y, dA1);
                dA2 = fmaf(rax, cv.z, dA2); dA3 = fmaf(rax, cv.w, dA3);
                dB0 = fmaf(rbx, cv.x, dB0); dB1 = fmaf(rbx, cv.y, dB1);
                dB2 = fmaf(rbx, cv.z, dB2); dB3 = fmaf(rbx, cv.w, dB3);
            }
        }

        float4 nv = *reinterpret_cast<const float4*>(&cnorm[jb]);
        // mimic reference rounding: (rr - 2*dot) + norm
        float vA0 = fmaf(-2.f, dA0, rrA) + nv.x;
        float vA1 = fmaf(-2.f, dA1, rrA) + nv.y;
        float vA2 = fmaf(-2.f, dA2, rrA) + nv.z;
        float vA3 = fmaf(-2.f, dA3, rrA) + nv.w;
        float vB0 = fmaf(-2.f, dB0, rrB) + nv.x;
        float vB1 = fmaf(-2.f, dB1, rrB) + nv.y;
        float vB2 = fmaf(-2.f, dB2, rrB) + nv.z;
        float vB3 = fmaf(-2.f, dB3, rrB) + nv.w;

        float bvA = vA0; int biA = jb;
        if (vA1 < bvA) { bvA = vA1; biA = jb + 1; }
        if (vA2 < bvA) { bvA = vA2; biA = jb + 2; }
        if (vA3 < bvA) { bvA = vA3; biA = jb + 3; }
        float bvB = vB0; int biB = jb;
        if (vB1 < bvB) { bvB = vB1; biB = jb + 1; }
        if (vB2 < bvB) { bvB = vB2; biB = jb + 2; }
        if (vB3 < bvB) { bvB = vB3; biB = jb + 3; }

#pragma unroll
        for (int off = 32; off; off >>= 1) {
            float ovA = __shfl_xor(bvA, off); int oiA = __shfl_xor(biA, off);
            if (ovA < bvA || (ovA == bvA && oiA < biA)) { bvA = ovA; biA = oiA; }
            float ovB = __shfl_xor(bvB, off); int oiB = __shfl_xor(biB, off);
            if (ovB < bvB || (ovB == bvB && oiB < biB)) { bvB = ovB; biB = oiB; }
        }

        float2 qa = *reinterpret_cast<const float2*>(&cb[(long)biA * EDIM + 2 * lane]);
        float2 qb = *reinterpret_cast<const float2*>(&cb[(long)biB * EDIM + 2 * lane]);
        float2 nrA; nrA.x = rvA.x - qa.x; nrA.y = rvA.y - qa.y;
        float2 nrB; nrB.x = rvB.x - qb.x; nrB.y = rvB.y - qb.y;
        *reinterpret_cast<float2*>(&resout[rA * EDIM + 2 * lane]) = nrA;
        *reinterpret_cast<float2*>(&resout[rB * EDIM + 2 * lane]) = nrB;

        if (lane == 0) {
            local_loss += bvA + bvB;
            idxf[rA * NLEV + level] = (float)biA;
            idxf[rB * NLEV + level] = (float)biB;
        }
    }
    if (lane == 0) loss_part[(long)level * 2048 + wg] = local_loss;
}

// x_q = z - res  (written to aligned ws buffer and to the (unaligned) d_out slot)
__global__ __launch_bounds__(256)
void finalize_xq(const float* __restrict__ z, const float* __restrict__ res,
                 float* __restrict__ xq_ws, float* __restrict__ xq_out) {
    long i = (long)blockIdx.x * blockDim.x + threadIdx.x;   // float4 index
    float4 zv = reinterpret_cast<const float4*>(z)[i];
    float4 rv = reinterpret_cast<const float4*>(res)[i];
    float4 v;
    v.x = zv.x - rv.x; v.y = zv.y - rv.y; v.z = zv.z - rv.z; v.w = zv.w - rv.w;
    reinterpret_cast<float4*>(xq_ws)[i] = v;
    long b = i * 4;
    xq_out[b + 0] = v.x; xq_out[b + 1] = v.y;
    xq_out[b + 2] = v.z; xq_out[b + 3] = v.w;
}

__global__ __launch_bounds__(256)
void loss_final(const float* __restrict__ part, float* __restrict__ out) {
    __shared__ float s[256];
    float acc = 0.f;
    for (int i = threadIdx.x; i < NLEV * 2048; i += 256) acc += part[i];
    s[threadIdx.x] = acc;
    __syncthreads();
    for (int st = 128; st; st >>= 1) {
        if (threadIdx.x < st) s[threadIdx.x] += s[threadIdx.x + st];
        __syncthreads();
    }
    if (threadIdx.x == 0)
        out[0] = s[0] * (1.001f / (4.0f * (float)N_ROWS * (float)EDIM));
}

// ============================================================================
extern "C" void kernel_launch(void* const* d_in, const int* in_sizes, int n_in,
                              void* d_out, int out_size, void* d_ws, size_t ws_size,
                              hipStream_t stream) {
    const float* x  = (const float*)d_in[0];
    const float* ew[4] = {(const float*)d_in[1], (const float*)d_in[3],
                          (const float*)d_in[5], (const float*)d_in[7]};
    const float* eb[4] = {(const float*)d_in[2], (const float*)d_in[4],
                          (const float*)d_in[6], (const float*)d_in[8]};
    const float* dw[4] = {(const float*)d_in[9],  (const float*)d_in[11],
                          (const float*)d_in[13], (const float*)d_in[15]};
    const float* db[4] = {(const float*)d_in[10], (const float*)d_in[12],
                          (const float*)d_in[14], (const float*)d_in[16]};
    const float* cbs = (const float*)d_in[17];

    float* out = (float*)d_out;
    const long LOSS_OFF = (long)N_ROWS * 768;          // 50331648
    const long IDX_OFF  = LOSS_OFF + 1;                // 50331649
    const long XQ_OFF   = IDX_OFF + (long)N_ROWS * 4;  // 50593793

    // ---- workspace layout (floats) ----
    float* wsf = (float*)d_ws;
    long off = 0;
    float* zf    = wsf + off; off += (long)N_ROWS * EDIM;   // 8.4M
    float* res   = wsf + off; off += (long)N_ROWS * EDIM;
    float* xq    = wsf + off; off += (long)N_ROWS * EDIM;
    float* lossp = wsf + off; off += NLEV * 2048;
    off = (off + 63) & ~63L;
    const long fixed = off;

    long R = 8192;
    while (R > 128) {
        long need_bytes = (fixed + R * (2048 + 1024 + 512)) * 4;
        if ((size_t)need_bytes <= ws_size) break;
        R >>= 1;
    }
    float* bufA = wsf + off; off += R * 2048;
    float* bufB = wsf + off; off += R * 1024;
    float* bufC = wsf + off;

    const int nchunks = N_ROWS / (int)R;
    dim3 blk(256);

    // ---- encoder (chunked) ----
    for (int c = 0; c < nchunks; ++c) {
        const float* xc = x + (long)c * R * 768;
        sgemm128<1><<<dim3(2048 / 128, R / 128), blk, 0, stream>>>(xc,   ew[0], eb[0], bufA, 768,  2048);
        sgemm128<1><<<dim3(1024 / 128, R / 128), blk, 0, stream>>>(bufA, ew[1], eb[1], bufB, 2048, 1024);
        sgemm128<1><<<dim3(512  / 128, R / 128), blk, 0, stream>>>(bufB, ew[2], eb[2], bufC, 1024, 512);
        sgemm128<0><<<dim3(128  / 128, R / 128), blk, 0, stream>>>(bufC, ew[3], eb[3],
                                                                   zf + (long)c * R * EDIM, 512, 128);
    }

    // ---- residual VQ (full N) ----
    for (int l = 0; l < NLEV; ++l)
        vq_level<<<256, 512, 0, stream>>>(l == 0 ? zf : res, res, cbs, l,
                                          lossp, out + IDX_OFF);

    finalize_xq<<<(N_ROWS * EDIM / 4) / 256, 256, 0, stream>>>(zf, res, xq, out + XQ_OFF);
    loss_final<<<1, 256, 0, stream>>>(lossp, out + LOSS_OFF);

    // ---- decoder (chunked) ----
    for (int c = 0; c < nchunks; ++c) {
        sgemm128<1><<<dim3(512  / 128, R / 128), blk, 0, stream>>>(xq + (long)c * R * EDIM,
                                                                   dw[0], db[0], bufC, 128,  512);
        sgemm128<1><<<dim3(1024 / 128, R / 128), blk, 0, stream>>>(bufC, dw[1], db[1], bufB, 512,  1024);
        sgemm128<1><<<dim3(2048 / 128, R / 128), blk, 0, stream>>>(bufB, dw[2], db[2], bufA, 1024, 2048);
        sgemm128<0><<<dim3(768  / 128, R / 128), blk, 0, stream>>>(bufA, dw[3], db[3],
                                                                   out + (long)c * R * 768, 2048, 768);
    }
}

// Round 2
// 4795.514 us; speedup vs baseline: 2.9000x; 2.9000x over previous
//
#include <hip/hip_runtime.h>
#include <hip/hip_bf16.h>
#include <cstdint>

#define N_ROWS   65536
#define EDIM     128
#define CBSZ     256
#define NLEV     4

typedef _Float16 f16x8 __attribute__((ext_vector_type(8)));
typedef _Float16 f16x4 __attribute__((ext_vector_type(4)));
typedef float    f32x4 __attribute__((ext_vector_type(4)));

__device__ __forceinline__ void gload_lds16(const void* g, void* l) {
    __builtin_amdgcn_global_load_lds(
        (const __attribute__((address_space(1))) void*)g,
        (__attribute__((address_space(3))) void*)l, 16, 0, 0);
}

// ============================================================================
// MFMA GEMM: C[R x M] = act(A[R x K] @ W[K x M] + bias)
// A given as fp16 split (Ah + Al = fp32 A); W given pre-transposed+split:
// Wth/Wtl are [M][K] (row m = column m of W).
// NPROD=3: hi*hi + hi*lo + lo*hi (fp32-like).  NPROD=1: hi*hi only.
// WRITE: 0 = fp32 to Cf;  1 = fp16 hi->Ch and lo->Cl;  2 = fp16 hi only.
// Tile: 128x128, BK=32, 256 threads (4 waves, 2x2), 64x64 per wave,
// mfma_f32_16x16x32_f16.  LDS layout [k8][128][8] -> linear global_load_lds
// dest + conflict-free contiguous ds_read_b128 fragments.
// ============================================================================
template<int NPROD, int WRITE, int RELU>
__global__ __launch_bounds__(256)
void hgemm(const _Float16* __restrict__ Ah, const _Float16* __restrict__ Al,
           const _Float16* __restrict__ Wth, const _Float16* __restrict__ Wtl,
           const float* __restrict__ bias,
           float* __restrict__ Cf, _Float16* __restrict__ Ch, _Float16* __restrict__ Cl,
           int K, int M) {
    constexpr int NOPS = (NPROD == 3) ? 2 : 1;
    __shared__ __align__(16) _Float16 As[NOPS][4][128][8];
    __shared__ __align__(16) _Float16 Bs[NOPS][4][128][8];

    const int t    = threadIdx.x;
    const int w    = t >> 6, lane = t & 63;
    const int wr   = w >> 1, wc   = w & 1;
    const int er   = lane & 15, kq = lane >> 4;
    const long row0 = (long)blockIdx.y * 128;
    const int  col0 = blockIdx.x * 128;

    f32x4 acc[4][4];
#pragma unroll
    for (int m = 0; m < 4; ++m)
#pragma unroll
        for (int n = 0; n < 4; ++n) {
            f32x4 z = {0.f, 0.f, 0.f, 0.f};
            acc[m][n] = z;
        }

    for (int k0 = 0; k0 < K; k0 += 32) {
        // stage: NOPS*16 chunks of 1KB (64 lanes x 16B), wave-uniform LDS dest
#pragma unroll
        for (int i = 0; i < NOPS * 4; ++i) {
            const int c    = w + 4 * i;
            const int k8   = c & 3;
            const int half = (c >> 2) & 1;
            const int mat  = c >> 3;
            const int r    = half * 64 + lane;
            const _Float16* src;
            _Float16* dst;
            if (mat == 0)      { src = Ah  + (row0 + r) * (long)K + k0 + k8 * 8; dst = &As[0][k8][half * 64][0]; }
            else if (mat == 1) { src = Wth + (col0 + r) * (long)K + k0 + k8 * 8; dst = &Bs[0][k8][half * 64][0]; }
            else if (mat == 2) { src = Al  + (row0 + r) * (long)K + k0 + k8 * 8; dst = &As[NOPS - 1][k8][half * 64][0]; }
            else               { src = Wtl + (col0 + r) * (long)K + k0 + k8 * 8; dst = &Bs[NOPS - 1][k8][half * 64][0]; }
            gload_lds16(src, dst);
        }
        __syncthreads();

        f16x8 ah[4], bh[4];
#pragma unroll
        for (int m = 0; m < 4; ++m) ah[m] = *(const f16x8*)&As[0][kq][wr * 64 + m * 16 + er][0];
#pragma unroll
        for (int n = 0; n < 4; ++n) bh[n] = *(const f16x8*)&Bs[0][kq][wc * 64 + n * 16 + er][0];

        if (NPROD == 3) {
            f16x8 al[4], bl[4];
#pragma unroll
            for (int m = 0; m < 4; ++m) al[m] = *(const f16x8*)&As[NOPS - 1][kq][wr * 64 + m * 16 + er][0];
#pragma unroll
            for (int n = 0; n < 4; ++n) bl[n] = *(const f16x8*)&Bs[NOPS - 1][kq][wc * 64 + n * 16 + er][0];
#pragma unroll
            for (int m = 0; m < 4; ++m)
#pragma unroll
                for (int n = 0; n < 4; ++n) {
                    acc[m][n] = __builtin_amdgcn_mfma_f32_16x16x32_f16(ah[m], bh[n], acc[m][n], 0, 0, 0);
                    acc[m][n] = __builtin_amdgcn_mfma_f32_16x16x32_f16(ah[m], bl[n], acc[m][n], 0, 0, 0);
                    acc[m][n] = __builtin_amdgcn_mfma_f32_16x16x32_f16(al[m], bh[n], acc[m][n], 0, 0, 0);
                }
        } else {
#pragma unroll
            for (int m = 0; m < 4; ++m)
#pragma unroll
                for (int n = 0; n < 4; ++n)
                    acc[m][n] = __builtin_amdgcn_mfma_f32_16x16x32_f16(ah[m], bh[n], acc[m][n], 0, 0, 0);
        }
        __syncthreads();
    }

    // epilogue: C[row][col], row = row0 + wr*64 + m*16 + kq*4 + r, col = col0 + wc*64 + n*16 + er
#pragma unroll
    for (int n = 0; n < 4; ++n) {
        const int col = col0 + wc * 64 + n * 16 + er;
        const float bv = bias[col];
#pragma unroll
        for (int m = 0; m < 4; ++m) {
            const long rbase = row0 + wr * 64 + m * 16 + kq * 4;
#pragma unroll
            for (int r = 0; r < 4; ++r) {
                float v = acc[m][n][r] + bv;
                if (RELU) v = fmaxf(v, 0.f);
                const long idx = (rbase + r) * M + col;
                if (WRITE == 0) {
                    Cf[idx] = v;
                } else {
                    _Float16 h = (_Float16)v;
                    Ch[idx] = h;
                    if (WRITE == 1) Cl[idx] = (_Float16)(v - (float)h);
                }
            }
        }
    }
}

// ============================================================================
// Prep: W[K][M] fp32 -> Wt hi/lo fp16 [M][K]
// ============================================================================
__global__ __launch_bounds__(256)
void splitWT(const float* __restrict__ W, _Float16* __restrict__ th,
             _Float16* __restrict__ tl, int K, int M) {
    long i = (long)blockIdx.x * 256 + threadIdx.x;
    if (i >= (long)K * M) return;
    int m = (int)(i / K), k = (int)(i % K);
    float v = W[(long)k * M + m];
    _Float16 h = (_Float16)v;
    th[i] = h;
    tl[i] = (_Float16)(v - (float)h);
}

__global__ __launch_bounds__(256)
void split_pair(const float* __restrict__ s, _Float16* __restrict__ h,
                _Float16* __restrict__ l, long n4) {
    long i = (long)blockIdx.x * 256 + threadIdx.x;
    if (i >= n4) return;
    float4 v = ((const float4*)s)[i];
    float a[4] = {v.x, v.y, v.z, v.w};
    f16x4 hv, lv;
#pragma unroll
    for (int j = 0; j < 4; ++j) {
        _Float16 hh = (_Float16)a[j];
        hv[j] = hh;
        lv[j] = (_Float16)(a[j] - (float)hh);
    }
    *(f16x4*)&h[i * 4] = hv;
    *(f16x4*)&l[i * 4] = lv;
}

// ============================================================================
// VQ level (unchanged from R1, fp32): one wave per row-pair, codebook
// transposed in LDS, exact first-min tie-break.
// ============================================================================
__global__ __launch_bounds__(512)
void vq_level(const float* __restrict__ resin, float* __restrict__ resout,
              const float* __restrict__ codebooks, int level,
              float* __restrict__ loss_part, float* __restrict__ idxf) {
    __shared__ float ct[EDIM][CBSZ + 4];
    __shared__ float cnorm[CBSZ];
    __shared__ float res_row[8][2][EDIM];

    const float* cb = codebooks + (long)level * CBSZ * EDIM;

    for (int e = threadIdx.x; e < CBSZ * EDIM; e += 512) {
        int j = e >> 7, d = e & 127;
        ct[d][j] = cb[e];
    }
    __syncthreads();
    for (int j = threadIdx.x; j < CBSZ; j += 512) {
        float s = 0.f;
        for (int d = 0; d < EDIM; ++d) s = fmaf(ct[d][j], ct[d][j], s);
        cnorm[j] = s;
    }
    __syncthreads();

    const int w    = threadIdx.x >> 6;
    const int lane = threadIdx.x & 63;
    const int wg   = blockIdx.x * 8 + w;
    const int jb   = lane * 4;
    float local_loss = 0.f;

    for (int p = 0; p < 16; ++p) {
        const long rA = (long)wg + (long)(2 * p) * 2048;
        const long rB = rA + 2048;

        float2 rvA = *reinterpret_cast<const float2*>(&resin[rA * EDIM + 2 * lane]);
        float2 rvB = *reinterpret_cast<const float2*>(&resin[rB * EDIM + 2 * lane]);
        res_row[w][0][2 * lane] = rvA.x; res_row[w][0][2 * lane + 1] = rvA.y;
        res_row[w][1][2 * lane] = rvB.x; res_row[w][1][2 * lane + 1] = rvB.y;

        float rrA = rvA.x * rvA.x + rvA.y * rvA.y;
        float rrB = rvB.x * rvB.x + rvB.y * rvB.y;
#pragma unroll
        for (int off = 32; off; off >>= 1) {
            rrA += __shfl_xor(rrA, off);
            rrB += __shfl_xor(rrB, off);
        }

        float dA0 = 0, dA1 = 0, dA2 = 0, dA3 = 0;
        float dB0 = 0, dB1 = 0, dB2 = 0, dB3 = 0;
        for (int d = 0; d < EDIM; d += 4) {
            float4 ra = *reinterpret_cast<const float4*>(&res_row[w][0][d]);
            float4 rb = *reinterpret_cast<const float4*>(&res_row[w][1][d]);
            const float* rap = &ra.x;
            const float* rbp = &rb.x;
#pragma unroll
            for (int dd = 0; dd < 4; ++dd) {
                float4 cv = *reinterpret_cast<const float4*>(&ct[d + dd][jb]);
                float rax = rap[dd], rbx = rbp[dd];
                dA0 = fmaf(rax, cv.x, dA0); dA1 = fmaf(rax, cv.y, dA1);
                dA2 = fmaf(rax, cv.z, dA2); dA3 = fmaf(rax, cv.w, dA3);
                dB0 = fmaf(rbx, cv.x, dB0); dB1 = fmaf(rbx, cv.y, dB1);
                dB2 = fmaf(rbx, cv.z, dB2); dB3 = fmaf(rbx, cv.w, dB3);
            }
        }

        float4 nv = *reinterpret_cast<const float4*>(&cnorm[jb]);
        float vA0 = fmaf(-2.f, dA0, rrA) + nv.x;
        float vA1 = fmaf(-2.f, dA1, rrA) + nv.y;
        float vA2 = fmaf(-2.f, dA2, rrA) + nv.z;
        float vA3 = fmaf(-2.f, dA3, rrA) + nv.w;
        float vB0 = fmaf(-2.f, dB0, rrB) + nv.x;
        float vB1 = fmaf(-2.f, dB1, rrB) + nv.y;
        float vB2 = fmaf(-2.f, dB2, rrB) + nv.z;
        float vB3 = fmaf(-2.f, dB3, rrB) + nv.w;

        float bvA = vA0; int biA = jb;
        if (vA1 < bvA) { bvA = vA1; biA = jb + 1; }
        if (vA2 < bvA) { bvA = vA2; biA = jb + 2; }
        if (vA3 < bvA) { bvA = vA3; biA = jb + 3; }
        float bvB = vB0; int biB = jb;
        if (vB1 < bvB) { bvB = vB1; biB = jb + 1; }
        if (vB2 < bvB) { bvB = vB2; biB = jb + 2; }
        if (vB3 < bvB) { bvB = vB3; biB = jb + 3; }

#pragma unroll
        for (int off = 32; off; off >>= 1) {
            float ovA = __shfl_xor(bvA, off); int oiA = __shfl_xor(biA, off);
            if (ovA < bvA || (ovA == bvA && oiA < biA)) { bvA = ovA; biA = oiA; }
            float ovB = __shfl_xor(bvB, off); int oiB = __shfl_xor(biB, off);
            if (ovB < bvB || (ovB == bvB && oiB < biB)) { bvB = ovB; biB = oiB; }
        }

        float2 qa = *reinterpret_cast<const float2*>(&cb[(long)biA * EDIM + 2 * lane]);
        float2 qb = *reinterpret_cast<const float2*>(&cb[(long)biB * EDIM + 2 * lane]);
        float2 nrA; nrA.x = rvA.x - qa.x; nrA.y = rvA.y - qa.y;
        float2 nrB; nrB.x = rvB.x - qb.x; nrB.y = rvB.y - qb.y;
        *reinterpret_cast<float2*>(&resout[rA * EDIM + 2 * lane]) = nrA;
        *reinterpret_cast<float2*>(&resout[rB * EDIM + 2 * lane]) = nrB;

        if (lane == 0) {
            local_loss += bvA + bvB;
            idxf[rA * NLEV + level] = (float)biA;
            idxf[rB * NLEV + level] = (float)biB;
        }
    }
    if (lane == 0) loss_part[(long)level * 2048 + wg] = local_loss;
}

// x_q = z - res : fp32 scalar to d_out slot (odd offset), fp16 hi for decoder
__global__ __launch_bounds__(256)
void finalize_xq(const float* __restrict__ z, const float* __restrict__ res,
                 _Float16* __restrict__ xqh, float* __restrict__ xq_out) {
    long i = (long)blockIdx.x * 256 + threadIdx.x;   // float4 index
    float4 zv = ((const float4*)z)[i];
    float4 rv = ((const float4*)res)[i];
    float vx = zv.x - rv.x, vy = zv.y - rv.y, vz = zv.z - rv.z, vw = zv.w - rv.w;
    f16x4 hv = {(_Float16)vx, (_Float16)vy, (_Float16)vz, (_Float16)vw};
    *(f16x4*)&xqh[i * 4] = hv;
    long b = i * 4;
    xq_out[b + 0] = vx; xq_out[b + 1] = vy;
    xq_out[b + 2] = vz; xq_out[b + 3] = vw;
}

__global__ __launch_bounds__(256)
void loss_final(const float* __restrict__ part, float* __restrict__ out) {
    __shared__ float s[256];
    float acc = 0.f;
    for (int i = threadIdx.x; i < NLEV * 2048; i += 256) acc += part[i];
    s[threadIdx.x] = acc;
    __syncthreads();
    for (int st = 128; st; st >>= 1) {
        if (threadIdx.x < st) s[threadIdx.x] += s[threadIdx.x + st];
        __syncthreads();
    }
    if (threadIdx.x == 0)
        out[0] = s[0] * (1.001f / (4.0f * (float)N_ROWS * (float)EDIM));
}

// ============================================================================
extern "C" void kernel_launch(void* const* d_in, const int* in_sizes, int n_in,
                              void* d_out, int out_size, void* d_ws, size_t ws_size,
                              hipStream_t stream) {
    const float* x  = (const float*)d_in[0];
    const float* ew[4] = {(const float*)d_in[1], (const float*)d_in[3],
                          (const float*)d_in[5], (const float*)d_in[7]};
    const float* eb[4] = {(const float*)d_in[2], (const float*)d_in[4],
                          (const float*)d_in[6], (const float*)d_in[8]};
    const float* dw[4] = {(const float*)d_in[9],  (const float*)d_in[11],
                          (const float*)d_in[13], (const float*)d_in[15]};
    const float* db[4] = {(const float*)d_in[10], (const float*)d_in[12],
                          (const float*)d_in[14], (const float*)d_in[16]};
    const float* cbs = (const float*)d_in[17];

    float* out = (float*)d_out;
    const long LOSS_OFF = (long)N_ROWS * 768;
    const long IDX_OFF  = LOSS_OFF + 1;
    const long XQ_OFF   = IDX_OFF + (long)N_ROWS * 4;

    const int encK[4] = {768, 2048, 1024, 512}, encM[4] = {2048, 1024, 512, 128};
    const int decK[4] = {128, 512, 1024, 2048}, decM[4] = {512, 1024, 2048, 768};

    // ---- workspace: fp32 region then fp16 region ----
    float* wsf = (float*)d_ws;
    long o32 = 0;
    float* zf    = wsf + o32; o32 += (long)N_ROWS * EDIM;
    float* res   = wsf + o32; o32 += (long)N_ROWS * EDIM;
    float* lossp = wsf + o32; o32 += NLEV * 2048;
    o32 = (o32 + 7) & ~7L;   // 32B-align fp16 region

    _Float16* wsh = (_Float16*)(wsf + o32);
    long oh = 0;
    _Float16* xqh = wsh + oh; oh += (long)N_ROWS * EDIM;
    _Float16 *ewh[4], *ewl[4], *dwh[4], *dwl[4];
    for (int j = 0; j < 4; ++j) {
        long n = (long)encK[j] * encM[j];
        ewh[j] = wsh + oh; oh += n;
        ewl[j] = wsh + oh; oh += n;
    }
    for (int j = 0; j < 4; ++j) {
        long n = (long)decK[j] * decM[j];
        dwh[j] = wsh + oh; oh += n;
        dwl[j] = wsh + oh; oh += n;
    }
    const long fixed_h = oh;

    long R = 8192;
    while (R > 1024) {
        size_t need = (size_t)o32 * 4 + (size_t)(fixed_h + R * 8704) * 2;
        if (need <= ws_size) break;
        R >>= 1;
    }
    _Float16* xh  = wsh + oh; oh += R * 768;
    _Float16* xl  = wsh + oh; oh += R * 768;
    _Float16* a2h = wsh + oh; oh += R * 2048;
    _Float16* a2l = wsh + oh; oh += R * 2048;
    _Float16* a1h = wsh + oh; oh += R * 1024;
    _Float16* a1l = wsh + oh; oh += R * 1024;
    _Float16* a0h = wsh + oh; oh += R * 512;
    _Float16* a0l = wsh + oh; oh += R * 512;

    // ---- prep: weight transpose + split (one-time, ~0.2 ms) ----
    for (int j = 0; j < 4; ++j) {
        long n = (long)encK[j] * encM[j];
        splitWT<<<dim3((unsigned)((n + 255) / 256)), 256, 0, stream>>>(ew[j], ewh[j], ewl[j], encK[j], encM[j]);
        n = (long)decK[j] * decM[j];
        splitWT<<<dim3((unsigned)((n + 255) / 256)), 256, 0, stream>>>(dw[j], dwh[j], dwl[j], decK[j], decM[j]);
    }

    const int nchunks = N_ROWS / (int)R;
    const dim3 blk(256);

    // ---- encoder: fp16x2 3-product MFMA ----
    for (int c = 0; c < nchunks; ++c) {
        split_pair<<<dim3((unsigned)((R * 768 / 4 + 255) / 256)), blk, 0, stream>>>(
            x + (long)c * R * 768, xh, xl, R * 768 / 4);
        hgemm<3,1,1><<<dim3(16, R / 128), blk, 0, stream>>>(xh,  xl,  ewh[0], ewl[0], eb[0], nullptr, a2h, a2l, 768,  2048);
        hgemm<3,1,1><<<dim3(8,  R / 128), blk, 0, stream>>>(a2h, a2l, ewh[1], ewl[1], eb[1], nullptr, a1h, a1l, 2048, 1024);
        hgemm<3,1,1><<<dim3(4,  R / 128), blk, 0, stream>>>(a1h, a1l, ewh[2], ewl[2], eb[2], nullptr, a0h, a0l, 1024, 512);
        hgemm<3,0,0><<<dim3(1,  R / 128), blk, 0, stream>>>(a0h, a0l, ewh[3], ewl[3], eb[3],
                                                            zf + (long)c * R * EDIM, nullptr, nullptr, 512, 128);
    }

    // ---- residual VQ (fp32, exact) ----
    for (int l = 0; l < NLEV; ++l)
        vq_level<<<256, 512, 0, stream>>>(l == 0 ? zf : res, res, cbs, l, lossp, out + IDX_OFF);

    finalize_xq<<<(N_ROWS * EDIM / 4) / 256, blk, 0, stream>>>(zf, res, xqh, out + XQ_OFF);
    loss_final<<<1, blk, 0, stream>>>(lossp, out + LOSS_OFF);

    // ---- decoder: single fp16 MFMA ----
    for (int c = 0; c < nchunks; ++c) {
        hgemm<1,2,1><<<dim3(4,  R / 128), blk, 0, stream>>>(xqh + (long)c * R * EDIM, nullptr, dwh[0], nullptr, db[0],
                                                            nullptr, a0h, nullptr, 128,  512);
        hgemm<1,2,1><<<dim3(8,  R / 128), blk, 0, stream>>>(a0h, nullptr, dwh[1], nullptr, db[1],
                                                            nullptr, a1h, nullptr, 512,  1024);
        hgemm<1,2,1><<<dim3(16, R / 128), blk, 0, stream>>>(a1h, nullptr, dwh[2], nullptr, db[2],
                                                            nullptr, a2h, nullptr, 1024, 2048);
        hgemm<1,0,0><<<dim3(6,  R / 128), blk, 0, stream>>>(a2h, nullptr, dwh[3], nullptr, db[3],
                                                            out + (long)c * R * 768, nullptr, nullptr, 2048, 768);
    }
}